// Round 3
// baseline (315.686 us; speedup 1.0000x reference)
//
#include <hip/hip_runtime.h>

// F0 via autocorrelation argmax — round 3: fp32 hot loop + fp64 fallback.
//   SR=16000, HOP=256, FRAME_LEN=512, pad=256, T=163840, B=64, n_frames=641
//   lags p in [32,256), 224 lags. Normalization is a positive per-frame
//   scalar -> argmax unaffected.
// Strategy: compute raw autocorrelation in fp32 (2 cyc/MAC vs fp64's 4, no
// converts). Then find top-2 over lags; if gap > GAP_B (>> rigorous fp32
// error bound ~6e-3), the fp32 argmax provably equals the exact argmax.
// Otherwise re-run the block with the proven fp64 path (round-2 code).
// Branch is block-uniform and input-deterministic -> graph-replay safe.

#define SR_F 16000.0f
#define HOP 256
#define FRAME_LEN 512
#define PAD 256
#define T_LEN 163840
#define N_FRAMES 641
#define MIN_PERIOD 32
#define N_LAGS 224      // lags 32..255, groups of 8
#define NSEGS 8
#define S_LEN 576       // 512 data + 64 zero pad (max read idx 549)
#define GAP_B 0.0625f

__global__ __launch_bounds__(256) void f0_kernel(const float* __restrict__ wav,
                                                 float* __restrict__ out) {
    __shared__ float  s[S_LEN];
    __shared__ double red_d[N_LAGS * NSEGS]; // fp64 partials; aliased as float for fp32 pass
    __shared__ float  rv[256];
    __shared__ float  rv2[256];
    __shared__ int    ri[256];
    __shared__ double dv[256];
    __shared__ int    di[256];
    __shared__ int    need64;

    const int bf = blockIdx.x;             // b * N_FRAMES + f
    const int b  = bf / N_FRAMES;
    const int f  = bf - b * N_FRAMES;
    const float* __restrict__ x = wav + (size_t)b * T_LEN;
    const int tid = threadIdx.x;

    // Stage frame (reflect pad at signal edges) + zero tail.
    const int base = f * HOP - PAD;
    for (int t = tid; t < FRAME_LEN; t += 256) {
        int idx = base + t;
        if (idx < 0) idx = -idx;
        if (idx >= T_LEN) idx = 2 * (T_LEN - 1) - idx;
        s[t] = x[idx];
    }
    if (tid < (S_LEN - FRAME_LEN)) s[FRAME_LEN + tid] = 0.0f;
    __syncthreads();

    const int g   = tid >> 3;              // lag group: 8 lags, p0 = 32+8g
    const int seg = tid & 7;
    const int p0  = MIN_PERIOD + (g << 3);
    const float4* s4 = (const float4*)s;
    float* red_f = (float*)red_d;

    // ---------- fp32 pass: 8 lags x 16 t per trip ----------
    if (tid < N_LAGS) {
        float acc[8];
        #pragma unroll
        for (int j = 0; j < 8; ++j) acc[j] = 0.0f;
        const int n16 = (FRAME_LEN - p0 + 15) >> 4;
        for (int ch = seg; ch < n16; ch += NSEGS) {
            const int t = ch << 4;
            float a[16], w[24];
            const int aq = t >> 2;
            const int wq = (t + p0) >> 2;  // t%16==0, p0%8==0 -> aligned
            #pragma unroll
            for (int q = 0; q < 4; ++q) {
                float4 v = s4[aq + q];
                a[4*q+0]=v.x; a[4*q+1]=v.y; a[4*q+2]=v.z; a[4*q+3]=v.w;
            }
            #pragma unroll
            for (int q = 0; q < 6; ++q) {
                float4 v = s4[wq + q];
                w[4*q+0]=v.x; w[4*q+1]=v.y; w[4*q+2]=v.z; w[4*q+3]=v.w;
            }
            #pragma unroll
            for (int j = 0; j < 8; ++j) {
                #pragma unroll
                for (int i = 0; i < 16; ++i)
                    acc[j] = __builtin_fmaf(a[i], w[i + j], acc[j]);
            }
        }
        #pragma unroll
        for (int j = 0; j < 8; ++j)
            red_f[(((g << 3) + j) << 3) + seg] = acc[j];
    }
    __syncthreads();

    // Seg-sum (fixed pairwise order) + top-2 tree over lags.
    float mv = -__builtin_inff(), mv2 = -__builtin_inff();
    int   mi = 0x7fffffff;
    if (tid < N_LAGS) {
        const float* r = &red_f[tid << 3];
        mv = ((r[0]+r[1]) + (r[2]+r[3])) + ((r[4]+r[5]) + (r[6]+r[7]));
        mi = tid;
    }
    rv[tid] = mv; rv2[tid] = mv2; ri[tid] = mi;
    __syncthreads();
    for (int st = 128; st > 0; st >>= 1) {
        if (tid < st) {
            float va = rv[tid],      vb = rv[tid + st];
            float sa = rv2[tid],     sb = rv2[tid + st];
            int   ia = ri[tid],      ib = ri[tid + st];
            if (vb > va || (vb == va && ib < ia)) {
                rv[tid] = vb; ri[tid] = ib; rv2[tid] = fmaxf(va, sb);
            } else {
                rv2[tid] = fmaxf(vb, sa);
            }
        }
        __syncthreads();
    }
    if (tid == 0) need64 = (rv[0] - rv2[0] <= GAP_B) ? 1 : 0;
    __syncthreads();

    if (need64) {
        // ---------- fp64 fallback (proven round-2 path) ----------
        double acc[8];
        #pragma unroll
        for (int j = 0; j < 8; ++j) acc[j] = 0.0;
        if (tid < N_LAGS) {
            const int n8 = (FRAME_LEN - p0 + 7) >> 3;
            for (int ch = seg; ch < n8; ch += NSEGS) {
                const int t = ch << 3;
                const float4 a0 = s4[t >> 2];
                const float4 a1 = s4[(t >> 2) + 1];
                const int wq = (t + p0) >> 2;
                const float4 w0 = s4[wq];
                const float4 w1 = s4[wq + 1];
                const float4 w2 = s4[wq + 2];
                const float4 w3 = s4[wq + 3];
                const double a[8] = {(double)a0.x,(double)a0.y,(double)a0.z,(double)a0.w,
                                     (double)a1.x,(double)a1.y,(double)a1.z,(double)a1.w};
                const double w[16] = {(double)w0.x,(double)w0.y,(double)w0.z,(double)w0.w,
                                      (double)w1.x,(double)w1.y,(double)w1.z,(double)w1.w,
                                      (double)w2.x,(double)w2.y,(double)w2.z,(double)w2.w,
                                      (double)w3.x,(double)w3.y,(double)w3.z,(double)w3.w};
                #pragma unroll
                for (int j = 0; j < 8; ++j) {
                    #pragma unroll
                    for (int i = 0; i < 8; ++i)
                        acc[j] = fma(a[i], w[i + j], acc[j]);
                }
            }
            #pragma unroll
            for (int j = 0; j < 8; ++j)
                red_d[(((g << 3) + j) << 3) + seg] = acc[j];
        }
        __syncthreads();

        double dvv = -__builtin_inf();
        int dii = 0x7fffffff;
        if (tid < N_LAGS) {
            const double* r = &red_d[tid << 3];
            dvv = ((r[0]+r[1]) + (r[2]+r[3])) + ((r[4]+r[5]) + (r[6]+r[7]));
            dii = tid;
        }
        dv[tid] = dvv; di[tid] = dii;
        __syncthreads();
        for (int st = 128; st > 0; st >>= 1) {
            if (tid < st) {
                double v1 = dv[tid], v2 = dv[tid + st];
                int    i1 = di[tid], i2 = di[tid + st];
                if (v2 > v1 || (v2 == v1 && i2 < i1)) {
                    dv[tid] = v2; di[tid] = i2;
                }
            }
            __syncthreads();
        }
        if (tid == 0) {
            float period = (float)(di[0] + MIN_PERIOD);
            float f0 = SR_F / (period + 1e-8f);
            out[bf] = fminf(fmaxf(f0, 50.0f), 500.0f);
        }
    } else if (tid == 0) {
        float period = (float)(ri[0] + MIN_PERIOD);
        float f0 = SR_F / (period + 1e-8f);
        out[bf] = fminf(fmaxf(f0, 50.0f), 500.0f);
    }
}

extern "C" void kernel_launch(void* const* d_in, const int* in_sizes, int n_in,
                              void* d_out, int out_size, void* d_ws, size_t ws_size,
                              hipStream_t stream) {
    const float* wav = (const float*)d_in[0]; // (64, 1, 163840) fp32
    float* out = (float*)d_out;               // (64, 641) fp32
    const int n_blocks = 64 * N_FRAMES;       // 41024
    f0_kernel<<<n_blocks, 256, 0, stream>>>(wav, out);
}

// Round 4
// 306.009 us; speedup vs baseline: 1.0316x; 1.0316x over previous
//
#include <hip/hip_runtime.h>

// F0 via autocorrelation argmax — round 4: swizzled LDS + 16x16 fp32 tile.
//   SR=16000, HOP=256, FRAME_LEN=512, pad=256, T=163840, B=64, n_frames=641
//   lags p in [32,256), 224 lags. Per-frame normalization is a positive
//   scalar -> argmax of RAW autocorrelation equals reference argmax.
//
// Round-3 lesson (counters): 64B-strided float4 LDS reads -> 4-way bank
// conflicts (8.8e7 cyc) dominated. Fix: XOR swizzle at float4 granularity,
//   phys_q = q ^ ((q>>3)&7)   (bijection on any multiple-of-8 range)
// which spreads our {q0+4m} access sets across all 8 bank-quads (<=2-3 way).
//
// Tile: 16 lags x 16 t per trip = 256 FMAs from 12 ds_read_b128.
// Trip count is exactly 2 for every lag group (no divergence).
// fp32 result accepted iff top1-top2 gap > GAP_B (rigorous fp32 error bound
// ~2e-3 << 0.0625); else block-uniform rerun in fp64 (exact argmax).

#define SR_F 16000.0f
#define HOP 256
#define FRAME_LEN 512
#define PAD 256
#define T_LEN 163840
#define N_FRAMES 641
#define MIN_PERIOD 32
#define N_LAGS 224
#define NGROUPS 14      // 16 lags per group
#define NSEGS 16
#define S_Q 144         // float4 slots (576 floats); multiple of 8 for swizzle
#define RSTRIDE 17      // padded seg stride for partials
#define GAP_B 0.0625f

__device__ __forceinline__ int swz(int q) { return q ^ ((q >> 3) & 7); }

__global__ __launch_bounds__(256, 1) void f0_kernel(const float* __restrict__ wav,
                                                    float* __restrict__ out) {
    __shared__ float  s[S_Q * 4];                 // swizzled frame (2304 B)
    __shared__ double red_d[N_LAGS * RSTRIDE];    // partials; aliased float for fp32
    __shared__ float  rv[256], rv2[256];
    __shared__ int    ri[256];
    __shared__ double dv[256];
    __shared__ int    di[256];
    __shared__ int    need64;

    const int bf = blockIdx.x;                    // b * N_FRAMES + f
    const int b  = bf / N_FRAMES;
    const int f  = bf - b * N_FRAMES;
    const float* __restrict__ x = wav + (size_t)b * T_LEN;
    const int tid = threadIdx.x;

    // ---- stage frame (reflect pad at signal edges) into swizzled LDS ----
    const int base = f * HOP - PAD;
    for (int t = tid; t < FRAME_LEN; t += 256) {
        int idx = base + t;
        if (idx < 0) idx = -idx;
        if (idx >= T_LEN) idx = 2 * (T_LEN - 1) - idx;
        s[(swz(t >> 2) << 2) | (t & 3)] = x[idx];
    }
    {   // zero-pad logical floats 512..575 (covers max window read 527)
        int t = FRAME_LEN + tid;
        if (t < S_Q * 4) s[(swz(t >> 2) << 2) | (t & 3)] = 0.0f;
    }
    __syncthreads();

    const int g   = tid >> 4;                     // lag group (16 lags), p0 = 32+16g
    const int seg = tid & 15;                     // t-segment
    const int p0  = MIN_PERIOD + (g << 4);
    const float4* s4 = (const float4*)s;
    float* red_f = (float*)red_d;

    // ---------------- fp32 pass: 16 lags x 16 t per trip ----------------
    if (g < NGROUPS) {
        float acc[16];
        #pragma unroll
        for (int j = 0; j < 16; ++j) acc[j] = 0.0f;
        const int n16 = (FRAME_LEN - p0 + 15) >> 4;   // 17..30 -> always 2 trips
        #pragma unroll
        for (int k = 0; k < 2; ++k) {
            const int ch = seg + (k << 4);
            if (ch < n16) {
                const int t  = ch << 4;
                const int qa = t >> 2;
                const int qw = (t + p0) >> 2;
                float a[16], w[32];
                #pragma unroll
                for (int q = 0; q < 4; ++q) {
                    float4 v = s4[swz(qa + q)];
                    a[4*q+0]=v.x; a[4*q+1]=v.y; a[4*q+2]=v.z; a[4*q+3]=v.w;
                }
                #pragma unroll
                for (int q = 0; q < 8; ++q) {
                    float4 v = s4[swz(qw + q)];
                    w[4*q+0]=v.x; w[4*q+1]=v.y; w[4*q+2]=v.z; w[4*q+3]=v.w;
                }
                #pragma unroll
                for (int j = 0; j < 16; ++j) {
                    #pragma unroll
                    for (int i = 0; i < 16; ++i)
                        acc[j] = __builtin_fmaf(a[i], w[i + j], acc[j]);
                }
            }
        }
        #pragma unroll
        for (int j = 0; j < 16; ++j)
            red_f[((g << 4) + j) * RSTRIDE + seg] = acc[j];
    }
    __syncthreads();

    // ---- seg-sum (fixed pairwise order) + top-2 tree over lags ----
    float mv = -__builtin_inff(), mv2 = -__builtin_inff();
    int   mi = 0x7fffffff;
    if (tid < N_LAGS) {
        const float* r = &red_f[tid * RSTRIDE];
        float t0 = (r[0]+r[1]) + (r[2]+r[3]);
        float t1 = (r[4]+r[5]) + (r[6]+r[7]);
        float t2 = (r[8]+r[9]) + (r[10]+r[11]);
        float t3 = (r[12]+r[13]) + (r[14]+r[15]);
        mv = (t0 + t1) + (t2 + t3);
        mi = tid;
    }
    rv[tid] = mv; rv2[tid] = mv2; ri[tid] = mi;
    __syncthreads();
    for (int st = 128; st > 0; st >>= 1) {
        if (tid < st) {
            float va = rv[tid],  vb = rv[tid + st];
            float sa = rv2[tid], sb = rv2[tid + st];
            int   ia = ri[tid],  ib = ri[tid + st];
            if (vb > va || (vb == va && ib < ia)) {
                rv[tid] = vb; ri[tid] = ib; rv2[tid] = fmaxf(va, sb);
            } else {
                rv2[tid] = fmaxf(vb, sa);
            }
        }
        __syncthreads();
    }
    if (tid == 0) need64 = (rv[0] - rv2[0] <= GAP_B) ? 1 : 0;
    __syncthreads();

    if (need64) {
        // ------------- fp64 fallback (exact argmax), rare -------------
        if (g < NGROUPS) {
            double acc[16];
            #pragma unroll
            for (int j = 0; j < 16; ++j) acc[j] = 0.0;
            const int n16 = (FRAME_LEN - p0 + 15) >> 4;
            #pragma unroll
            for (int k = 0; k < 2; ++k) {
                const int ch = seg + (k << 4);
                if (ch < n16) {
                    const int t  = ch << 4;
                    const int qa = t >> 2;
                    const int qw = (t + p0) >> 2;
                    double a[16], w[32];
                    #pragma unroll
                    for (int q = 0; q < 4; ++q) {
                        float4 v = s4[swz(qa + q)];
                        a[4*q+0]=(double)v.x; a[4*q+1]=(double)v.y;
                        a[4*q+2]=(double)v.z; a[4*q+3]=(double)v.w;
                    }
                    #pragma unroll
                    for (int q = 0; q < 8; ++q) {
                        float4 v = s4[swz(qw + q)];
                        w[4*q+0]=(double)v.x; w[4*q+1]=(double)v.y;
                        w[4*q+2]=(double)v.z; w[4*q+3]=(double)v.w;
                    }
                    #pragma unroll
                    for (int j = 0; j < 16; ++j) {
                        #pragma unroll
                        for (int i = 0; i < 16; ++i)
                            acc[j] = fma(a[i], w[i + j], acc[j]);
                    }
                }
            }
            #pragma unroll
            for (int j = 0; j < 16; ++j)
                red_d[((g << 4) + j) * RSTRIDE + seg] = acc[j];
        }
        __syncthreads();

        double dvv = -__builtin_inf();
        int dii = 0x7fffffff;
        if (tid < N_LAGS) {
            const double* r = &red_d[tid * RSTRIDE];
            double t0 = (r[0]+r[1]) + (r[2]+r[3]);
            double t1 = (r[4]+r[5]) + (r[6]+r[7]);
            double t2 = (r[8]+r[9]) + (r[10]+r[11]);
            double t3 = (r[12]+r[13]) + (r[14]+r[15]);
            dvv = (t0 + t1) + (t2 + t3);
            dii = tid;
        }
        dv[tid] = dvv; di[tid] = dii;
        __syncthreads();
        for (int st = 128; st > 0; st >>= 1) {
            if (tid < st) {
                double v1 = dv[tid], v2 = dv[tid + st];
                int    i1 = di[tid], i2 = di[tid + st];
                if (v2 > v1 || (v2 == v1 && i2 < i1)) {
                    dv[tid] = v2; di[tid] = i2;
                }
            }
            __syncthreads();
        }
        if (tid == 0) {
            float period = (float)(di[0] + MIN_PERIOD);
            float f0 = SR_F / (period + 1e-8f);
            out[bf] = fminf(fmaxf(f0, 50.0f), 500.0f);
        }
    } else if (tid == 0) {
        float period = (float)(ri[0] + MIN_PERIOD);
        float f0 = SR_F / (period + 1e-8f);
        out[bf] = fminf(fmaxf(f0, 50.0f), 500.0f);
    }
}

extern "C" void kernel_launch(void* const* d_in, const int* in_sizes, int n_in,
                              void* d_out, int out_size, void* d_ws, size_t ws_size,
                              hipStream_t stream) {
    const float* wav = (const float*)d_in[0]; // (64, 1, 163840) fp32
    float* out = (float*)d_out;               // (64, 641) fp32
    const int n_blocks = 64 * N_FRAMES;       // 41024
    f0_kernel<<<n_blocks, 256, 0, stream>>>(wav, out);
}